// Round 6
// baseline (76.313 us; speedup 1.0000x reference)
//
#include <hip/hip_runtime.h>
#include <hip/hip_bf16.h>

#define NB 4
#define N_NODES 100000
#define E_EDGES 160000
#define EA_E 80000
#define HID 128
#define ED 16

#define TILE_M 256
#define THREADS 512

typedef __attribute__((ext_vector_type(8))) short bf16x8;
typedef __attribute__((ext_vector_type(4))) float f32x4;
typedef __attribute__((ext_vector_type(8))) unsigned short u16x8;

__device__ __forceinline__ unsigned short f2bf(float f) {
    union { __hip_bfloat16 b; unsigned short u; } v;
    v.b = __float2bfloat16(f);   // RTNE
    return v.u;
}

__device__ __forceinline__ bf16x8 cvt8(f32x4 a, f32x4 c) {
    bf16x8 r;
    r[0] = (short)f2bf(a[0]); r[1] = (short)f2bf(a[1]);
    r[2] = (short)f2bf(a[2]); r[3] = (short)f2bf(a[3]);
    r[4] = (short)f2bf(c[0]); r[5] = (short)f2bf(c[1]);
    r[6] = (short)f2bf(c[2]); r[7] = (short)f2bf(c[3]);
    return r;
}

__device__ __forceinline__ void gll16(const void* g, void* l) {
    __builtin_amdgcn_global_load_lds(
        (const __attribute__((address_space(1))) unsigned int*)g,
        (__attribute__((address_space(3))) unsigned int*)l, 16, 0, 0);
}

// ---- pre-kernel: W1 (fp32 [272][128]) -> bf16 fragments in d_ws ----
// W1F[((c*8 + ni)*64 + lane)*8 + j]; n = ni*16 + (lane&15), k = c*32 + (lane>>4)*8 + j
__global__ void prep_w1(const float* __restrict__ W1, unsigned short* __restrict__ W1F) {
    const int cb   = blockIdx.x;      // 0..71 = c*8 + ni
    const int c    = cb >> 3;
    const int ni   = cb & 7;
    const int lane = threadIdx.x;     // 0..63
    const int fr   = lane & 15;
    const int fq   = lane >> 4;
    const int n    = ni * 16 + fr;
    u16x8 v;
    #pragma unroll
    for (int j = 0; j < 8; ++j) {
        int k = c * 32 + fq * 8 + j;
        float f = (k < 272) ? W1[(size_t)k * HID + n] : 0.f;
        v[j] = f2bf(f);
    }
    *reinterpret_cast<u16x8*>(W1F + ((size_t)(cb * 64 + lane)) * 8) = v;
}

__global__ __launch_bounds__(THREADS, 4) void actor_head_mfma(
    const float* __restrict__ h,            // [B][N][128]
    const int*   __restrict__ edge_index,   // [2][E]
    const float* __restrict__ edge_attr,    // [B][E][16]
    const int*   __restrict__ etype,        // [EA]
    const unsigned short* __restrict__ W1F, // bf16 fragment-ordered W1 (72 KB)
    const float* __restrict__ b1,           // [128]
    const float* __restrict__ W2,           // [128][2]
    const float* __restrict__ b2,           // [2]
    float*       __restrict__ out)          // [B][EA/2][2]
{
    __shared__ unsigned short bws[36864];   // full B, 72 KB, loaded once
    __shared__ int sel[3][TILE_M];

    const int b  = blockIdx.y;
    const int e0 = blockIdx.x * TILE_M;
    const int t  = threadIdx.x;

    if (t < TILE_M) {
        int idx = e0 + t;
        if (idx >= EA_E) idx = EA_E - 1;    // tail clamp (stores guarded below)
        int ei = etype[idx];
        sel[2][t] = ei;
        sel[0][t] = edge_index[ei];
        sel[1][t] = edge_index[E_EDGES + ei];
    }

    const int lane = t & 63;
    const int wid  = t >> 6;          // 0..7
    const int wm   = wid * 32;        // wave owns rows wm..wm+31, all 128 cols
    const int fr   = lane & 15;
    const int fq   = lane >> 4;

    // ---- prologue: DMA all of W1F into LDS (only barrier in the kernel) ----
    #pragma unroll
    for (int r = 0; r < 9; ++r)
        gll16(W1F + (size_t)(r * 4096 + wid * 512 + lane * 8),
              &bws[r * 4096 + wid * 512]);

    f32x4 acc[2][8];
    #pragma unroll
    for (int i = 0; i < 2; ++i)
        #pragma unroll
        for (int j = 0; j < 8; ++j) acc[i][j] = (f32x4){0.f, 0.f, 0.f, 0.f};

    __syncthreads();   // sel + bws ready; no further barriers

    // ---- per-lane gather pointers (reassigned at the h_recv -> h_sent switch) ----
    const int r0 = wm + fr, r1 = wm + 16 + fr;
    const float* pa0 = h + ((size_t)b * N_NODES + sel[0][r0]) * HID;
    const float* pa1 = h + ((size_t)b * N_NODES + sel[0][r1]) * HID;

    f32x4 tv[4];
    {
        const float* q0 = pa0 + fq * 8;
        const float* q1 = pa1 + fq * 8;
        tv[0] = *reinterpret_cast<const f32x4*>(q0);
        tv[1] = *reinterpret_cast<const f32x4*>(q0 + 4);
        tv[2] = *reinterpret_cast<const f32x4*>(q1);
        tv[3] = *reinterpret_cast<const f32x4*>(q1 + 4);
    }

    #pragma unroll
    for (int c = 0; c < 9; ++c) {
        // convert current chunk's gathers (waits counted vmcnt), freeing tv
        bf16x8 af0 = cvt8(tv[0], tv[1]);
        bf16x8 af1 = cvt8(tv[2], tv[3]);

        // issue next chunk's gathers; they fly across this chunk's MFMAs
        if (c < 8) {
            const int cn = c + 1;
            if (cn == 4) {   // switch to h_sent rows
                pa0 = h + ((size_t)b * N_NODES + sel[1][r0]) * HID;
                pa1 = h + ((size_t)b * N_NODES + sel[1][r1]) * HID;
            }
            if (cn < 8) {
                const float* q0 = pa0 + (cn & 3) * 32 + fq * 8;
                const float* q1 = pa1 + (cn & 3) * 32 + fq * 8;
                tv[0] = *reinterpret_cast<const f32x4*>(q0);
                tv[1] = *reinterpret_cast<const f32x4*>(q0 + 4);
                tv[2] = *reinterpret_cast<const f32x4*>(q1);
                tv[3] = *reinterpret_cast<const f32x4*>(q1 + 4);
            } else {
                if (fq < 2) {   // edge_attr chunk: only k<16 valid (W1F zero-padded above)
                    const float* q0 = edge_attr + ((size_t)b * E_EDGES + sel[2][r0]) * ED + fq * 8;
                    const float* q1 = edge_attr + ((size_t)b * E_EDGES + sel[2][r1]) * ED + fq * 8;
                    tv[0] = *reinterpret_cast<const f32x4*>(q0);
                    tv[1] = *reinterpret_cast<const f32x4*>(q0 + 4);
                    tv[2] = *reinterpret_cast<const f32x4*>(q1);
                    tv[3] = *reinterpret_cast<const f32x4*>(q1 + 4);
                } else {
                    tv[0] = tv[1] = tv[2] = tv[3] = (f32x4){0.f, 0.f, 0.f, 0.f};
                }
            }
        }

        // MFMAs for chunk c; B fragments from read-only LDS
        #pragma unroll
        for (int ni = 0; ni < 8; ++ni) {
            bf16x8 bw = *reinterpret_cast<const bf16x8*>(&bws[(c * 8 + ni) * 512 + lane * 8]);
            acc[0][ni] = __builtin_amdgcn_mfma_f32_16x16x32_bf16(af0, bw, acc[0][ni], 0, 0, 0);
            acc[1][ni] = __builtin_amdgcn_mfma_f32_16x16x32_bf16(af1, bw, acc[1][ni], 0, 0, 0);
        }
    }

    // ---------- epilogue: relu(+b1), @W2, pair-mean, +b2 ----------
    float b1v[8], w2a[8], w2b[8];
    #pragma unroll
    for (int ni = 0; ni < 8; ++ni) {
        int n = ni * 16 + fr;
        b1v[ni] = b1[n];
        w2a[ni] = W2[2 * n + 0];
        w2b[ni] = W2[2 * n + 1];
    }
    const float b20 = b2[0], b21 = b2[1];

    #pragma unroll
    for (int mi = 0; mi < 2; ++mi) {
        #pragma unroll
        for (int j = 0; j < 2; ++j) {
            // C/D rows fq*4 + 2j and fq*4 + 2j+1 form one output pair
            float s0 = 0.f, s1 = 0.f;
            #pragma unroll
            for (int ni = 0; ni < 8; ++ni) {
                float y0 = fmaxf(acc[mi][ni][2 * j]     + b1v[ni], 0.f);
                float y1 = fmaxf(acc[mi][ni][2 * j + 1] + b1v[ni], 0.f);
                float ys = y0 + y1;
                s0 = fmaf(ys, w2a[ni], s0);
                s1 = fmaf(ys, w2b[ni], s1);
            }
            #pragma unroll
            for (int off = 8; off >= 1; off >>= 1) {
                s0 += __shfl_xor(s0, off);
                s1 += __shfl_xor(s1, off);
            }
            if (fr == 0) {
                int mg = e0 + wm + mi * 16 + fq * 4 + 2 * j;   // even edge row
                if (mg < EA_E) {
                    size_t oi = ((size_t)b * (EA_E / 2) + (mg >> 1)) * 2;
                    out[oi + 0] = 0.5f * s0 + b20;
                    out[oi + 1] = 0.5f * s1 + b21;
                }
            }
        }
    }
}

extern "C" void kernel_launch(void* const* d_in, const int* in_sizes, int n_in,
                              void* d_out, int out_size, void* d_ws, size_t ws_size,
                              hipStream_t stream) {
    const float* h          = (const float*)d_in[0];
    const int*   edge_index = (const int*)d_in[1];
    const float* edge_attr  = (const float*)d_in[2];
    const int*   etype      = (const int*)d_in[3];
    const float* W1         = (const float*)d_in[4];
    const float* b1         = (const float*)d_in[5];
    const float* W2         = (const float*)d_in[6];
    const float* b2         = (const float*)d_in[7];
    float* out = (float*)d_out;

    unsigned short* W1F = (unsigned short*)d_ws;   // 72*64*8 ushorts = 73728 B

    prep_w1<<<72, 64, 0, stream>>>(W1, W1F);

    dim3 grid((EA_E + TILE_M - 1) / TILE_M, NB);   // 313 x 4
    actor_head_mfma<<<grid, THREADS, 0, stream>>>(
        h, edge_index, edge_attr, etype, W1F, b1, W2, b2, out);
}

// Round 7
// 72.785 us; speedup vs baseline: 1.0485x; 1.0485x over previous
//
#include <hip/hip_runtime.h>
#include <hip/hip_bf16.h>

#define NB 4
#define N_NODES 100000
#define E_EDGES 160000
#define EA_E 80000
#define HID 128
#define ED 16

#define TILE_M 128
#define THREADS 256
#define XPAD 40   // xs row length in ushort (32 used) -> 80B stride

typedef __attribute__((ext_vector_type(8))) short bf16x8;
typedef __attribute__((ext_vector_type(4))) float f32x4;
typedef __attribute__((ext_vector_type(8))) unsigned short u16x8;

__device__ __forceinline__ unsigned short f2bf(float f) {
    union { __hip_bfloat16 b; unsigned short u; } v;
    v.b = __float2bfloat16(f);   // RTNE
    return v.u;
}

__device__ __forceinline__ void gll16(const void* g, void* l) {
    __builtin_amdgcn_global_load_lds(
        (const __attribute__((address_space(1))) unsigned int*)g,
        (__attribute__((address_space(3))) unsigned int*)l, 16, 0, 0);
}

// ---- pre-kernel: W1 (fp32 [272][128]) -> bf16 fragments in d_ws ----
// W1F[((c*8 + ni)*64 + lane)*8 + j]; n = ni*16 + (lane&15), k = c*32 + (lane>>4)*8 + j
__global__ void prep_w1(const float* __restrict__ W1, unsigned short* __restrict__ W1F) {
    const int cb   = blockIdx.x;      // 0..71 = c*8 + ni
    const int c    = cb >> 3;
    const int ni   = cb & 7;
    const int lane = threadIdx.x;     // 0..63
    const int fr   = lane & 15;
    const int fq   = lane >> 4;
    const int n    = ni * 16 + fr;
    u16x8 v;
    #pragma unroll
    for (int j = 0; j < 8; ++j) {
        int k = c * 32 + fq * 8 + j;
        float f = (k < 272) ? W1[(size_t)k * HID + n] : 0.f;
        v[j] = f2bf(f);
    }
    *reinterpret_cast<u16x8*>(W1F + ((size_t)(cb * 64 + lane)) * 8) = v;
}

__global__ __launch_bounds__(THREADS, 4) void actor_head_mfma(
    const float* __restrict__ h,            // [B][N][128]
    const int*   __restrict__ edge_index,   // [2][E]
    const float* __restrict__ edge_attr,    // [B][E][16]
    const int*   __restrict__ etype,        // [EA]
    const unsigned short* __restrict__ W1F, // bf16 fragment-ordered W1
    const float* __restrict__ b1,           // [128]
    const float* __restrict__ W2,           // [128][2]
    const float* __restrict__ b2,           // [2]
    float*       __restrict__ out)          // [B][EA/2][2]
{
    __shared__ unsigned short xs[2][TILE_M][XPAD]; // x tile double buffer
    __shared__ unsigned short bws[2][4096];        // B chunk double buffer
    __shared__ int sel[3][TILE_M];

    const int b  = blockIdx.y;
    const int e0 = blockIdx.x * TILE_M;
    const int t  = threadIdx.x;

    if (t < TILE_M) {
        int ei = etype[e0 + t];
        sel[2][t] = ei;
        sel[0][t] = edge_index[ei];
        sel[1][t] = edge_index[E_EDGES + ei];
    }

    const int lane = t & 63;
    const int wid  = t >> 6;          // 0..3
    const int wm   = wid * 32;        // wave owns rows wm..wm+31, all 128 cols
    const int fr   = lane & 15;
    const int fq   = lane >> 4;

    // staging roles: 2 threads per x row, 16 floats each
    const int sm = t >> 1;
    const int sh = t & 1;

    f32x4 tv0[4], tv1[4];             // gather dbuf: chunk k lives in tv(k&1)
    f32x4 acc[2][8];
    #pragma unroll
    for (int i = 0; i < 2; ++i)
        #pragma unroll
        for (int j = 0; j < 8; ++j) acc[i][j] = (f32x4){0.f, 0.f, 0.f, 0.f};

    __syncthreads();   // sel visible

    const float* hr = h + ((size_t)b * N_NODES + sel[0][sm]) * HID + sh * 16;
    const float* hs = h + ((size_t)b * N_NODES + sel[1][sm]) * HID + sh * 16;
    const float* ea = edge_attr + ((size_t)b * E_EDGES + sel[2][sm]) * ED;

#define GATHER(dst, cn) do { if ((cn) <= 8) { \
    if ((cn) < 8) { \
        const float* q = (((cn) < 4) ? hr : hs) + ((cn) & 3) * 32; \
        dst[0] = *reinterpret_cast<const f32x4*>(q); \
        dst[1] = *reinterpret_cast<const f32x4*>(q + 4); \
        dst[2] = *reinterpret_cast<const f32x4*>(q + 8); \
        dst[3] = *reinterpret_cast<const f32x4*>(q + 12); \
    } else if (sh == 0) { \
        dst[0] = *reinterpret_cast<const f32x4*>(ea); \
        dst[1] = *reinterpret_cast<const f32x4*>(ea + 4); \
        dst[2] = *reinterpret_cast<const f32x4*>(ea + 8); \
        dst[3] = *reinterpret_cast<const f32x4*>(ea + 12); \
    } else { \
        dst[0] = dst[1] = dst[2] = dst[3] = (f32x4){0.f, 0.f, 0.f, 0.f}; \
    } } } while (0)

#define DMA_B(cn) do { if ((cn) <= 8) { \
    _Pragma("unroll") \
    for (int j2 = 0; j2 < 2; ++j2) \
        gll16(W1F + (size_t)(((cn) * 8 + j2 * 4 + wid) * 64 + lane) * 8, \
              &bws[(cn) & 1][(j2 * 4 + wid) * 512]); } } while (0)

#define CVT_STAGE(src, buf) do { u16x8 lo_, hi_; \
    _Pragma("unroll") \
    for (int j = 0; j < 4; ++j) { \
        lo_[j]     = f2bf(src[0][j]); lo_[4 + j] = f2bf(src[1][j]); \
        hi_[j]     = f2bf(src[2][j]); hi_[4 + j] = f2bf(src[3][j]); } \
    *reinterpret_cast<u16x8*>(&xs[(buf)][sm][sh * 16 + 0]) = lo_; \
    *reinterpret_cast<u16x8*>(&xs[(buf)][sm][sh * 16 + 8]) = hi_; } while (0)

#define MFMA_C(c) do { bf16x8 af0_, af1_; \
    af0_ = *reinterpret_cast<const bf16x8*>(&xs[(c) & 1][wm + fr][fq * 8]); \
    af1_ = *reinterpret_cast<const bf16x8*>(&xs[(c) & 1][wm + 16 + fr][fq * 8]); \
    _Pragma("unroll") \
    for (int ni = 0; ni < 8; ++ni) { \
        bf16x8 bw_ = *reinterpret_cast<const bf16x8*>(&bws[(c) & 1][ni * 512 + lane * 8]); \
        acc[0][ni] = __builtin_amdgcn_mfma_f32_16x16x32_bf16(af0_, bw_, acc[0][ni], 0, 0, 0); \
        acc[1][ni] = __builtin_amdgcn_mfma_f32_16x16x32_bf16(af1_, bw_, acc[1][ni], 0, 0, 0); } } while (0)

    // phase c: [gathers(c+2) issued FIRST -> age across whole phase]
    //          [DMA B(c+1)] [cvt tv(c+1) -> xs (stall-free: drained last barrier)]
    //          [MFMA c] [barrier]
#define PHASE(c, TVN, TVC) do { \
    GATHER(TVN, (c) + 2); \
    DMA_B((c) + 1); \
    CVT_STAGE(TVC, ((c) + 1) & 1); \
    MFMA_C(c); \
    __syncthreads(); } while (0)

    // ---- prologue ----
    GATHER(tv0, 0);
    DMA_B(0);
    GATHER(tv1, 1);        // flies while cvt below stalls on tv0
    CVT_STAGE(tv0, 0);
    __syncthreads();       // xs[0], bws[0] ready

    PHASE(0, tv0, tv1);
    PHASE(1, tv1, tv0);
    PHASE(2, tv0, tv1);
    PHASE(3, tv1, tv0);
    PHASE(4, tv0, tv1);
    PHASE(5, tv1, tv0);
    PHASE(6, tv0, tv1);    // gathers chunk 8 (edge_attr) -> tv0
    PHASE(7, tv1, tv0);    // GATHER(tv1,9) = no-op; cvt chunk 8
    MFMA_C(8);             // no barrier needed after

    // ---------- epilogue: relu(+b1), @W2, pair-mean, +b2 ----------
    float b1v[8], w2a[8], w2b[8];
    #pragma unroll
    for (int ni = 0; ni < 8; ++ni) {
        int n = ni * 16 + fr;
        b1v[ni] = b1[n];
        w2a[ni] = W2[2 * n + 0];
        w2b[ni] = W2[2 * n + 1];
    }
    const float b20 = b2[0], b21 = b2[1];

    #pragma unroll
    for (int mi = 0; mi < 2; ++mi) {
        #pragma unroll
        for (int j = 0; j < 2; ++j) {
            // C/D rows fq*4 + 2j and fq*4 + 2j+1 form one output pair
            float s0 = 0.f, s1 = 0.f;
            #pragma unroll
            for (int ni = 0; ni < 8; ++ni) {
                float y0 = fmaxf(acc[mi][ni][2 * j]     + b1v[ni], 0.f);
                float y1 = fmaxf(acc[mi][ni][2 * j + 1] + b1v[ni], 0.f);
                float ys = y0 + y1;
                s0 = fmaf(ys, w2a[ni], s0);
                s1 = fmaf(ys, w2b[ni], s1);
            }
            #pragma unroll
            for (int off = 8; off >= 1; off >>= 1) {
                s0 += __shfl_xor(s0, off);
                s1 += __shfl_xor(s1, off);
            }
            if (fr == 0) {
                int mg = e0 + wm + mi * 16 + fq * 4 + 2 * j;   // even edge row
                size_t oi = ((size_t)b * (EA_E / 2) + (mg >> 1)) * 2;
                out[oi + 0] = 0.5f * s0 + b20;
                out[oi + 1] = 0.5f * s1 + b21;
            }
        }
    }
}

extern "C" void kernel_launch(void* const* d_in, const int* in_sizes, int n_in,
                              void* d_out, int out_size, void* d_ws, size_t ws_size,
                              hipStream_t stream) {
    const float* h          = (const float*)d_in[0];
    const int*   edge_index = (const int*)d_in[1];
    const float* edge_attr  = (const float*)d_in[2];
    const int*   etype      = (const int*)d_in[3];
    const float* W1         = (const float*)d_in[4];
    const float* b1         = (const float*)d_in[5];
    const float* W2         = (const float*)d_in[6];
    const float* b2         = (const float*)d_in[7];
    float* out = (float*)d_out;

    unsigned short* W1F = (unsigned short*)d_ws;   // 72*64*8 ushorts = 73728 B

    prep_w1<<<72, 64, 0, stream>>>(W1, W1F);

    dim3 grid(EA_E / TILE_M, NB);   // 625 x 4
    actor_head_mfma<<<grid, THREADS, 0, stream>>>(
        h, edge_index, edge_attr, etype, W1F, b1, W2, b2, out);
}

// Round 8
// 57.824 us; speedup vs baseline: 1.3198x; 1.2587x over previous
//
#include <hip/hip_runtime.h>
#include <hip/hip_bf16.h>

#define NB 4
#define N_NODES 100000
#define E_EDGES 160000
#define EA_E 80000
#define HID 128
#define ED 16

#define TILE_M 128
#define THREADS 256
#define XPAD 40   // xs row length in ushort (32 used) -> 80B stride

typedef __attribute__((ext_vector_type(8))) short bf16x8;
typedef __attribute__((ext_vector_type(4))) float f32x4;
typedef __attribute__((ext_vector_type(8))) unsigned short u16x8;

__device__ __forceinline__ unsigned short f2bf(float f) {
    union { __hip_bfloat16 b; unsigned short u; } v;
    v.b = __float2bfloat16(f);   // RTNE
    return v.u;
}

__device__ __forceinline__ void gll16(const void* g, void* l) {
    __builtin_amdgcn_global_load_lds(
        (const __attribute__((address_space(1))) unsigned int*)g,
        (__attribute__((address_space(3))) unsigned int*)l, 16, 0, 0);
}

// ---- pre-kernel: W1 (fp32 [272][128]) -> bf16 fragments in d_ws ----
// W1F[((c*8 + ni)*64 + lane)*8 + j]; n = ni*16 + (lane&15), k = c*32 + (lane>>4)*8 + j
__global__ void prep_w1(const float* __restrict__ W1, unsigned short* __restrict__ W1F) {
    const int cb   = blockIdx.x;      // 0..71 = c*8 + ni
    const int c    = cb >> 3;
    const int ni   = cb & 7;
    const int lane = threadIdx.x;     // 0..63
    const int fr   = lane & 15;
    const int fq   = lane >> 4;
    const int n    = ni * 16 + fr;
    u16x8 v;
    #pragma unroll
    for (int j = 0; j < 8; ++j) {
        int k = c * 32 + fq * 8 + j;
        float f = (k < 272) ? W1[(size_t)k * HID + n] : 0.f;
        v[j] = f2bf(f);
    }
    *reinterpret_cast<u16x8*>(W1F + ((size_t)(cb * 64 + lane)) * 8) = v;
}

__global__ __launch_bounds__(THREADS, 3) void actor_head_mfma(
    const float* __restrict__ h,            // [B][N][128]
    const int*   __restrict__ edge_index,   // [2][E]
    const float* __restrict__ edge_attr,    // [B][E][16]
    const int*   __restrict__ etype,        // [EA]
    const unsigned short* __restrict__ W1F, // bf16 fragment-ordered W1
    const float* __restrict__ b1,           // [128]
    const float* __restrict__ W2,           // [128][2]
    const float* __restrict__ b2,           // [2]
    float*       __restrict__ out)          // [B][EA/2][2]
{
    __shared__ unsigned short xs[2][TILE_M][XPAD]; // x tile double buffer
    __shared__ unsigned short bws[2][4096];        // B chunk double buffer
    __shared__ int sel[3][TILE_M];

    const int b  = blockIdx.y;
    const int e0 = blockIdx.x * TILE_M;
    const int t  = threadIdx.x;

    if (t < TILE_M) {
        int ei = etype[e0 + t];
        sel[2][t] = ei;
        sel[0][t] = edge_index[ei];
        sel[1][t] = edge_index[E_EDGES + ei];
    }

    const int lane = t & 63;
    const int wid  = t >> 6;          // 0..3
    const int wm   = wid * 32;        // wave owns rows wm..wm+31, all 128 cols
    const int fr   = lane & 15;
    const int fq   = lane >> 4;

    // staging roles: 2 threads per x row, 16 floats each
    const int sm = t >> 1;
    const int sh = t & 1;

    f32x4 tv[4];
    f32x4 acc[2][8];
    #pragma unroll
    for (int i = 0; i < 2; ++i)
        #pragma unroll
        for (int j = 0; j < 8; ++j) acc[i][j] = (f32x4){0.f, 0.f, 0.f, 0.f};

    __syncthreads();   // sel visible (full barrier ok, once)

    const float* hr = h + ((size_t)b * N_NODES + sel[0][sm]) * HID + sh * 16;
    const float* hs = h + ((size_t)b * N_NODES + sel[1][sm]) * HID + sh * 16;
    const float* ea = edge_attr + ((size_t)b * E_EDGES + sel[2][sm]) * ED;

#define GATHER(cn) do { if ((cn) <= 8) { \
    if ((cn) < 8) { \
        const float* q = (((cn) < 4) ? hr : hs) + ((cn) & 3) * 32; \
        tv[0] = *reinterpret_cast<const f32x4*>(q); \
        tv[1] = *reinterpret_cast<const f32x4*>(q + 4); \
        tv[2] = *reinterpret_cast<const f32x4*>(q + 8); \
        tv[3] = *reinterpret_cast<const f32x4*>(q + 12); \
    } else if (sh == 0) { \
        tv[0] = *reinterpret_cast<const f32x4*>(ea); \
        tv[1] = *reinterpret_cast<const f32x4*>(ea + 4); \
        tv[2] = *reinterpret_cast<const f32x4*>(ea + 8); \
        tv[3] = *reinterpret_cast<const f32x4*>(ea + 12); \
    } else { \
        tv[0] = tv[1] = tv[2] = tv[3] = (f32x4){0.f, 0.f, 0.f, 0.f}; \
    } } } while (0)

#define DMA_B(cn) do { if ((cn) <= 8) { \
    _Pragma("unroll") \
    for (int j2 = 0; j2 < 2; ++j2) \
        gll16(W1F + (size_t)(((cn) * 8 + j2 * 4 + wid) * 64 + lane) * 8, \
              &bws[(cn) & 1][(j2 * 4 + wid) * 512]); } } while (0)

#define CVT_STAGE(buf) do { u16x8 lo_, hi_; \
    _Pragma("unroll") \
    for (int j = 0; j < 4; ++j) { \
        lo_[j]     = f2bf(tv[0][j]); lo_[4 + j] = f2bf(tv[1][j]); \
        hi_[j]     = f2bf(tv[2][j]); hi_[4 + j] = f2bf(tv[3][j]); } \
    *reinterpret_cast<u16x8*>(&xs[(buf)][sm][sh * 16 + 0]) = lo_; \
    *reinterpret_cast<u16x8*>(&xs[(buf)][sm][sh * 16 + 8]) = hi_; } while (0)

#define MFMA_C(c) do { bf16x8 af0_, af1_; \
    af0_ = *reinterpret_cast<const bf16x8*>(&xs[(c) & 1][wm + fr][fq * 8]); \
    af1_ = *reinterpret_cast<const bf16x8*>(&xs[(c) & 1][wm + 16 + fr][fq * 8]); \
    _Pragma("unroll") \
    for (int ni = 0; ni < 8; ++ni) { \
        bf16x8 bw_ = *reinterpret_cast<const bf16x8*>(&bws[(c) & 1][ni * 512 + lane * 8]); \
        acc[0][ni] = __builtin_amdgcn_mfma_f32_16x16x32_bf16(af0_, bw_, acc[0][ni], 0, 0, 0); \
        acc[1][ni] = __builtin_amdgcn_mfma_f32_16x16x32_bf16(af1_, bw_, acc[1][ni], 0, 0, 0); } } while (0)

    // ---- prologue ----
    DMA_B(0);                                   // glls oldest
    __builtin_amdgcn_sched_barrier(0);
    GATHER(0);
    CVT_STAGE(0);                               // compiler-counted vmcnt (drains glls too)
    GATHER(1);                                  // survives the raw barrier below
    __builtin_amdgcn_sched_barrier(0);
    asm volatile("s_waitcnt vmcnt(4) lgkmcnt(0)" ::: "memory");
    __builtin_amdgcn_sched_barrier(0);
    __builtin_amdgcn_s_barrier();               // xs[0], bws[0] ready

    // ---- main loop: raw barriers, counted vmcnt (T3/T4) ----
    for (int c = 0; c < 8; ++c) {
        DMA_B(c + 1);                           // 2 gll first -> oldest this phase
        __builtin_amdgcn_sched_barrier(0);      // pin: nothing moves above the glls
        CVT_STAGE((c + 1) & 1);                 // consumes prev-phase gathers (counted wait)
        GATHER(c + 2);                          // 4 loads (phases 0..5); stay in flight
        MFMA_C(c);
        __builtin_amdgcn_sched_barrier(0);
        if (c < 6) {
            // drain exactly the 2 glls (oldest); keep 4 gathers flying across the barrier
            asm volatile("s_waitcnt vmcnt(4) lgkmcnt(0)" ::: "memory");
        } else {
            // phases 6,7: gather count non-uniform (edge_attr sh-split / none) -> full drain
            asm volatile("s_waitcnt vmcnt(0) lgkmcnt(0)" ::: "memory");
        }
        __builtin_amdgcn_sched_barrier(0);
        __builtin_amdgcn_s_barrier();
    }
    MFMA_C(8);                                  // bws[0]/xs[0] finalized by phase-7 barrier

    // ---------- epilogue: relu(+b1), @W2, pair-mean, +b2 ----------
    float b1v[8], w2a[8], w2b[8];
    #pragma unroll
    for (int ni = 0; ni < 8; ++ni) {
        int n = ni * 16 + fr;
        b1v[ni] = b1[n];
        w2a[ni] = W2[2 * n + 0];
        w2b[ni] = W2[2 * n + 1];
    }
    const float b20 = b2[0], b21 = b2[1];

    #pragma unroll
    for (int mi = 0; mi < 2; ++mi) {
        #pragma unroll
        for (int j = 0; j < 2; ++j) {
            // C/D rows fq*4 + 2j and fq*4 + 2j+1 form one output pair
            float s0 = 0.f, s1 = 0.f;
            #pragma unroll
            for (int ni = 0; ni < 8; ++ni) {
                float y0 = fmaxf(acc[mi][ni][2 * j]     + b1v[ni], 0.f);
                float y1 = fmaxf(acc[mi][ni][2 * j + 1] + b1v[ni], 0.f);
                float ys = y0 + y1;
                s0 = fmaf(ys, w2a[ni], s0);
                s1 = fmaf(ys, w2b[ni], s1);
            }
            #pragma unroll
            for (int off = 8; off >= 1; off >>= 1) {
                s0 += __shfl_xor(s0, off);
                s1 += __shfl_xor(s1, off);
            }
            if (fr == 0) {
                int mg = e0 + wm + mi * 16 + fq * 4 + 2 * j;   // even edge row
                size_t oi = ((size_t)b * (EA_E / 2) + (mg >> 1)) * 2;
                out[oi + 0] = 0.5f * s0 + b20;
                out[oi + 1] = 0.5f * s1 + b21;
            }
        }
    }
}

extern "C" void kernel_launch(void* const* d_in, const int* in_sizes, int n_in,
                              void* d_out, int out_size, void* d_ws, size_t ws_size,
                              hipStream_t stream) {
    const float* h          = (const float*)d_in[0];
    const int*   edge_index = (const int*)d_in[1];
    const float* edge_attr  = (const float*)d_in[2];
    const int*   etype      = (const int*)d_in[3];
    const float* W1         = (const float*)d_in[4];
    const float* b1         = (const float*)d_in[5];
    const float* W2         = (const float*)d_in[6];
    const float* b2         = (const float*)d_in[7];
    float* out = (float*)d_out;

    unsigned short* W1F = (unsigned short*)d_ws;   // 72*64*8 ushorts = 73728 B

    prep_w1<<<72, 64, 0, stream>>>(W1, W1F);

    dim3 grid(EA_E / TILE_M, NB);   // 625 x 4
    actor_head_mfma<<<grid, THREADS, 0, stream>>>(
        h, edge_index, edge_attr, etype, W1F, b1, W2, b2, out);
}